// Round 1
// baseline (767.740 us; speedup 1.0000x reference)
//
#include <hip/hip_runtime.h>

#define NN 50000
#define NE 800000
// in order: node_features[NN*64], edge_features[NE*32], src[NE], dst[NE],
//           w_group[160], w_srcattn[96], w_lin[160*64]
// out: [NN*64] float32

// ---------------------------------------------------------------------------
// Pass 1: per-edge scores. Wave (64 lanes) per edge.
//   a = dot(e_ft, wg[0:32]) + dot(h_src, wg[32:96]) + dot(h_dst, wg[96:160])
//   t = dot(h_src, wa[0:64]);  u = dot(e_ft, wa[64:96])
//   den_src[src] += exp(a)   (softmax denom; max-subtraction skipped: scores ~N(0,0.6))
// ---------------------------------------------------------------------------
__global__ __launch_bounds__(256) void k_edge_score(
    const float* __restrict__ h, const float* __restrict__ ef,
    const int* __restrict__ src, const int* __restrict__ dst,
    const float* __restrict__ wg, const float* __restrict__ wa,
    float* __restrict__ den_src, float* __restrict__ ea,
    float* __restrict__ tt, float* __restrict__ uu)
{
    int edge = blockIdx.x * 4 + (threadIdx.x >> 6);
    if (edge >= NE) return;
    int lane = threadIdx.x & 63;
    int s = src[edge], d = dst[edge];
    float hs = h[(size_t)s * 64 + lane];
    float hd = h[(size_t)d * 64 + lane];
    float a  = hs * wg[32 + lane] + hd * wg[96 + lane];
    float tv = hs * wa[lane];
    float uv = 0.f;
    if (lane < 32) {
        float e = ef[(size_t)edge * 32 + lane];
        a  += e * wg[lane];
        uv  = e * wa[64 + lane];
    }
    #pragma unroll
    for (int off = 32; off; off >>= 1) {
        a  += __shfl_xor(a, off);
        tv += __shfl_xor(tv, off);
        uv += __shfl_xor(uv, off);
    }
    if (lane == 0) {
        float e = expf(a);
        ea[edge] = e;
        tt[edge] = tv;
        uu[edge] = uv;
        atomicAdd(&den_src[s], e);
    }
}

// ---------------------------------------------------------------------------
// Pass 2: scalar per edge. gamma = ea/den_src[src]; s = t + gamma*u;
//         den_dst[dst] += exp(s)
// ---------------------------------------------------------------------------
__global__ __launch_bounds__(256) void k_gamma_s(
    const int* __restrict__ src, const int* __restrict__ dst,
    const float* __restrict__ den_src,
    const float* __restrict__ ea, const float* __restrict__ tt,
    const float* __restrict__ uu,
    float* __restrict__ gm, float* __restrict__ es,
    float* __restrict__ den_dst)
{
    int e = blockIdx.x * blockDim.x + threadIdx.x;
    if (e >= NE) return;
    float g = ea[e] / den_src[src[e]];
    float sv = tt[e] + g * uu[e];
    float ex = expf(sv);
    gm[e] = g;
    es[e] = ex;
    atomicAdd(&den_dst[dst[e]], ex);
}

// ---------------------------------------------------------------------------
// Pass 3: scatter. Wave per edge. alpha = es/den_dst[dst];
//   accum[dst][0:64]  += alpha * h_src
//   accum[dst][64:96] += alpha * gamma * e_ft
// ---------------------------------------------------------------------------
__global__ __launch_bounds__(256) void k_scatter(
    const float* __restrict__ h, const float* __restrict__ ef,
    const int* __restrict__ src, const int* __restrict__ dst,
    const float* __restrict__ den_dst, const float* __restrict__ es,
    const float* __restrict__ gm, float* __restrict__ accum)
{
    int edge = blockIdx.x * 4 + (threadIdx.x >> 6);
    if (edge >= NE) return;
    int lane = threadIdx.x & 63;
    int s = src[edge], d = dst[edge];
    float alpha = es[edge] / den_dst[d];
    float v = alpha * h[(size_t)s * 64 + lane];
    atomicAdd(&accum[(size_t)d * 96 + lane], v);
    if (lane < 32) {
        float v2 = alpha * gm[edge] * ef[(size_t)edge * 32 + lane];
        atomicAdd(&accum[(size_t)d * 96 + 64 + lane], v2);
    }
}

// ---------------------------------------------------------------------------
// Pass 4: node update. out = relu(concat([h, accum]) @ w_lin)
// w_lin (160x64 = 40KB) staged in LDS; 4 nodes per block iteration;
// thread o = tid&63 computes output column o. wl[k*64+o]: lanes 0..31 and
// 32..63 hit banks 0..31 twice -> 2-way, free on gfx950.
// ---------------------------------------------------------------------------
__global__ __launch_bounds__(256) void k_node_update(
    const float* __restrict__ h, const float* __restrict__ accum,
    const float* __restrict__ wl_g, float* __restrict__ out)
{
    __shared__ float wl[160 * 64];
    for (int i = threadIdx.x; i < 160 * 64; i += 256) wl[i] = wl_g[i];
    __syncthreads();
    int o = threadIdx.x & 63;
    int nsub = threadIdx.x >> 6;
    for (int n = blockIdx.x * 4 + nsub; n < NN; n += gridDim.x * 4) {
        const float4* h4 = (const float4*)(h + (size_t)n * 64);
        const float4* a4 = (const float4*)(accum + (size_t)n * 96);
        float acc = 0.f;
        #pragma unroll
        for (int q = 0; q < 16; ++q) {
            float4 v = h4[q];
            int k = q * 4;
            acc += v.x * wl[(k + 0) * 64 + o] + v.y * wl[(k + 1) * 64 + o]
                 + v.z * wl[(k + 2) * 64 + o] + v.w * wl[(k + 3) * 64 + o];
        }
        #pragma unroll
        for (int q = 0; q < 24; ++q) {
            float4 v = a4[q];
            int k = 64 + q * 4;
            acc += v.x * wl[(k + 0) * 64 + o] + v.y * wl[(k + 1) * 64 + o]
                 + v.z * wl[(k + 2) * 64 + o] + v.w * wl[(k + 3) * 64 + o];
        }
        out[(size_t)n * 64 + o] = fmaxf(acc, 0.f);
    }
}

// ---------------------------------------------------------------------------
// Workspace layout (floats):
//   [0, NN)            den_src   (zeroed)
//   [NN, 2NN)          den_dst   (zeroed)
//   [2NN, 98NN)        accum     (zeroed)  NN*96
//   [98NN, +NE)        ea
//   +NE                tt
//   +NE                uu
//   +NE                es
//   +NE                gm
// total = 98*NN + 5*NE = 8.9M floats = 35.6 MB
// ---------------------------------------------------------------------------
extern "C" void kernel_launch(void* const* d_in, const int* in_sizes, int n_in,
                              void* d_out, int out_size, void* d_ws, size_t ws_size,
                              hipStream_t stream)
{
    const float* h  = (const float*)d_in[0];
    const float* ef = (const float*)d_in[1];
    const int*   src = (const int*)d_in[2];
    const int*   dst = (const int*)d_in[3];
    const float* wg = (const float*)d_in[4];
    const float* wa = (const float*)d_in[5];
    const float* wl = (const float*)d_in[6];
    float* out = (float*)d_out;

    float* ws = (float*)d_ws;
    float* den_src = ws;
    float* den_dst = ws + NN;
    float* accum   = ws + 2 * NN;
    float* ea = ws + 98 * NN;
    float* tt = ea + NE;
    float* uu = tt + NE;
    float* es = uu + NE;
    float* gm = es + NE;

    hipMemsetAsync(d_ws, 0, (size_t)(98 * NN) * sizeof(float), stream);

    k_edge_score<<<(NE + 3) / 4, 256, 0, stream>>>(h, ef, src, dst, wg, wa,
                                                   den_src, ea, tt, uu);
    k_gamma_s<<<(NE + 255) / 256, 256, 0, stream>>>(src, dst, den_src, ea, tt, uu,
                                                    gm, es, den_dst);
    k_scatter<<<(NE + 3) / 4, 256, 0, stream>>>(h, ef, src, dst, den_dst, es, gm,
                                                accum);
    k_node_update<<<1024, 256, 0, stream>>>(h, accum, wl, out);
}

// Round 2
// 597.665 us; speedup vs baseline: 1.2846x; 1.2846x over previous
//
#include <hip/hip_runtime.h>

#define NN 50000
#define NE 800000
// inputs: node_features[NN*64] f32, edge_features[NE*32] f32, src[NE] i32,
//         dst[NE] i32, w_group[160] f32, w_srcattn[96] f32, w_lin[160*64] f32
// out: [NN*64] f32

// ---------------------------------------------------------------------------
// Pass 1: thread-per-edge scoring.
//   a = [ef,h_src,h_dst]·wg ; t = h_src·wa[0:64] ; u = ef·wa[64:96]
//   ea=exp(a) (safe: |a|<~4), den_src[src]+=ea, cnt[dst]++ (histogram for CSR)
// Weights staged in LDS (broadcast ds_read_b128); rows read as float4.
// ---------------------------------------------------------------------------
__global__ __launch_bounds__(256) void k_edge(
    const float* __restrict__ h, const float* __restrict__ ef,
    const int* __restrict__ src, const int* __restrict__ dst,
    const float* __restrict__ wg, const float* __restrict__ wa,
    float* __restrict__ den_src, int* __restrict__ cnt,
    float* __restrict__ ea, float* __restrict__ tt, float* __restrict__ uu)
{
    __shared__ float4 lw[40];   // wg: [0:8)=ef, [8:24)=h_src, [24:40)=h_dst
    __shared__ float4 la[24];   // wa: [0:16)=h_src, [16:24)=ef
    int tid = threadIdx.x;
    if (tid < 40)      lw[tid]      = ((const float4*)wg)[tid];
    else if (tid < 64) la[tid - 40] = ((const float4*)wa)[tid - 40];
    __syncthreads();
    int e = blockIdx.x * 256 + tid;
    if (e >= NE) return;
    int s = src[e], d = dst[e];
    const float4* hs4 = (const float4*)(h + (size_t)s * 64);
    const float4* hd4 = (const float4*)(h + (size_t)d * 64);
    const float4* ef4 = (const float4*)(ef + (size_t)e * 32);
    float a = 0.f, t = 0.f, u = 0.f;
    #pragma unroll
    for (int q = 0; q < 8; ++q) {
        float4 v = ef4[q], w = lw[q], w2 = la[16 + q];
        a += v.x*w.x  + v.y*w.y  + v.z*w.z  + v.w*w.w;
        u += v.x*w2.x + v.y*w2.y + v.z*w2.z + v.w*w2.w;
    }
    #pragma unroll
    for (int q = 0; q < 16; ++q) {
        float4 v = hs4[q], w = lw[8 + q], w2 = la[q];
        a += v.x*w.x  + v.y*w.y  + v.z*w.z  + v.w*w.w;
        t += v.x*w2.x + v.y*w2.y + v.z*w2.z + v.w*w2.w;
    }
    #pragma unroll
    for (int q = 0; q < 16; ++q) {
        float4 v = hd4[q], w = lw[24 + q];
        a += v.x*w.x + v.y*w.y + v.z*w.z + v.w*w.w;
    }
    float ev = __expf(a);
    ea[e] = ev; tt[e] = t; uu[e] = u;
    atomicAdd(&den_src[s], ev);
    atomicAdd(&cnt[d], 1);
}

// ---------------------------------------------------------------------------
// Pass 2: exclusive scan of cnt[NN] -> off[NN+1]. One block, 1024 threads.
// ---------------------------------------------------------------------------
__global__ __launch_bounds__(1024) void k_scan(const int* __restrict__ cnt,
                                               int* __restrict__ off)
{
    __shared__ int ls[1024];
    int t = threadIdx.x;
    const int CH = (NN + 1023) / 1024;   // 49
    int b0 = t * CH, s = 0;
    for (int i = 0; i < CH; ++i) { int idx = b0 + i; if (idx < NN) s += cnt[idx]; }
    ls[t] = s;
    __syncthreads();
    for (int d = 1; d < 1024; d <<= 1) {
        int v = (t >= d) ? ls[t - d] : 0;
        __syncthreads();
        ls[t] += v;
        __syncthreads();
    }
    int run = ls[t] - s;                 // exclusive base for this chunk
    for (int i = 0; i < CH; ++i) {
        int idx = b0 + i;
        if (idx < NN) { off[idx] = run; run += cnt[idx]; }
    }
    if (t == 1023) off[NN] = run;        // == NE
}

// ---------------------------------------------------------------------------
// Pass 3: gamma = ea/den_src[src]; s = t + gamma*u; es = exp(s);
// route 16B record {src, edge, es, gamma} into its dst segment slot.
// (den_dst is NOT needed: segments are contiguous, reduce sums es inline.)
// ---------------------------------------------------------------------------
__global__ __launch_bounds__(256) void k_route(
    const int* __restrict__ src, const int* __restrict__ dst,
    const float* __restrict__ den_src, const float* __restrict__ ea,
    const float* __restrict__ tt, const float* __restrict__ uu,
    const int* __restrict__ off, int* __restrict__ cur,
    int4* __restrict__ rec)
{
    int e = blockIdx.x * 256 + threadIdx.x;
    if (e >= NE) return;
    int s = src[e], d = dst[e];
    float g  = ea[e] / den_src[s];
    float es = __expf(tt[e] + g * uu[e]);
    int pos = off[d] + atomicAdd(&cur[d], 1);
    rec[pos] = make_int4(s, e, __float_as_int(es), __float_as_int(g));
}

// ---------------------------------------------------------------------------
// Pass 4: wave-per-node segmented reduce. Lane l accumulates component l of
// the h-part (64) and, for l<32, component 64+l of the e-part. Denominator
// accumulated in the same loop; one normalized 384B store per node.
// ---------------------------------------------------------------------------
__global__ __launch_bounds__(256) void k_reduce(
    const float* __restrict__ h, const float* __restrict__ ef,
    const int* __restrict__ cnt, const int* __restrict__ off,
    const int4* __restrict__ rec, float* __restrict__ accum)
{
    int n = blockIdx.x * 4 + (threadIdx.x >> 6);
    if (n >= NN) return;
    int lane = threadIdx.x & 63;
    int deg = cnt[n], base = off[n];
    float acc = 0.f, acce = 0.f, den = 0.f;
    for (int j = 0; j < deg; ++j) {
        int4 r = rec[base + j];            // wave-uniform addr -> broadcast
        int   s  = r.x, e = r.y;
        float es = __int_as_float(r.z);
        float g  = __int_as_float(r.w);
        den += es;
        acc += es * h[(size_t)s * 64 + lane];
        if (lane < 32) acce += es * g * ef[(size_t)e * 32 + lane];
    }
    float inv = (deg > 0) ? 1.f / den : 0.f;
    accum[(size_t)n * 96 + lane] = acc * inv;
    if (lane < 32) accum[(size_t)n * 96 + 64 + lane] = acce * inv;
}

// ---------------------------------------------------------------------------
// Pass 5: out = relu(concat([h, accum]) @ w_lin). w_lin in 40KB LDS.
// ---------------------------------------------------------------------------
__global__ __launch_bounds__(256) void k_node_update(
    const float* __restrict__ h, const float* __restrict__ accum,
    const float* __restrict__ wl_g, float* __restrict__ out)
{
    __shared__ float wl[160 * 64];
    for (int i = threadIdx.x; i < 160 * 64; i += 256) wl[i] = wl_g[i];
    __syncthreads();
    int o = threadIdx.x & 63;
    int nsub = threadIdx.x >> 6;
    for (int n = blockIdx.x * 4 + nsub; n < NN; n += gridDim.x * 4) {
        const float4* h4 = (const float4*)(h + (size_t)n * 64);
        const float4* a4 = (const float4*)(accum + (size_t)n * 96);
        float acc = 0.f;
        #pragma unroll
        for (int q = 0; q < 16; ++q) {
            float4 v = h4[q];
            int k = q * 4;
            acc += v.x * wl[(k + 0) * 64 + o] + v.y * wl[(k + 1) * 64 + o]
                 + v.z * wl[(k + 2) * 64 + o] + v.w * wl[(k + 3) * 64 + o];
        }
        #pragma unroll
        for (int q = 0; q < 24; ++q) {
            float4 v = a4[q];
            int k = 64 + q * 4;
            acc += v.x * wl[(k + 0) * 64 + o] + v.y * wl[(k + 1) * 64 + o]
                 + v.z * wl[(k + 2) * 64 + o] + v.w * wl[(k + 3) * 64 + o];
        }
        out[(size_t)n * 64 + o] = fmaxf(acc, 0.f);
    }
}

// ---------------------------------------------------------------------------
// Workspace layout (4-byte units):
//   [0, NN)              den_src  (float, zeroed)
//   [NN, 2NN)            cnt      (int,   zeroed)
//   [2NN, 3NN)           cur      (int,   zeroed)
//   [3NN, 4NN+1)         off      (int)
//   [4NN+64, +4NE)       rec      (int4 x NE)  -- 16B aligned (4NN+64 % 4 == 0)
//   [4NN+64+4NE, +NE)    ea   \
//   +NE                  tt    }  aliased by accum (NN*96) in passes 4-5
//   +NE                  uu   /
// total = 4NN+64 + 4NE + max(3NE, 96NN) = ~32.8 MB
// ---------------------------------------------------------------------------
extern "C" void kernel_launch(void* const* d_in, const int* in_sizes, int n_in,
                              void* d_out, int out_size, void* d_ws, size_t ws_size,
                              hipStream_t stream)
{
    const float* h   = (const float*)d_in[0];
    const float* ef  = (const float*)d_in[1];
    const int*   src = (const int*)d_in[2];
    const int*   dst = (const int*)d_in[3];
    const float* wg  = (const float*)d_in[4];
    const float* wa  = (const float*)d_in[5];
    const float* wl  = (const float*)d_in[6];
    float* out = (float*)d_out;

    float* ws = (float*)d_ws;
    float* den_src = ws;
    int*   cnt = (int*)(ws + NN);
    int*   cur = (int*)(ws + 2 * NN);
    int*   off = (int*)(ws + 3 * NN);
    int4*  rec = (int4*)(ws + 4 * NN + 64);
    float* ea  = ws + 4 * NN + 64 + 4 * NE;
    float* tt  = ea + NE;
    float* uu  = tt + NE;
    float* accum = ea;   // aliases ea/tt/uu region (dead by pass 4)

    // zero den_src + cnt + cur (3*NN words)
    hipMemsetAsync(d_ws, 0, (size_t)(3 * NN) * sizeof(float), stream);

    k_edge<<<(NE + 255) / 256, 256, 0, stream>>>(h, ef, src, dst, wg, wa,
                                                 den_src, cnt, ea, tt, uu);
    k_scan<<<1, 1024, 0, stream>>>(cnt, off);
    k_route<<<(NE + 255) / 256, 256, 0, stream>>>(src, dst, den_src, ea, tt, uu,
                                                  off, cur, rec);
    k_reduce<<<(NN + 3) / 4, 256, 0, stream>>>(h, ef, cnt, off, rec, accum);
    k_node_update<<<1024, 256, 0, stream>>>(h, accum, wl, out);
}

// Round 3
// 484.587 us; speedup vs baseline: 1.5843x; 1.2334x over previous
//
#include <hip/hip_runtime.h>

#define NN 50000
#define NE 800000
// inputs: node_features[NN*64] f32, edge_features[NE*32] f32, src[NE] i32,
//         dst[NE] i32, w_group[160] f32, w_srcattn[96] f32, w_lin[160*64] f32
// out: [NN*64] f32

// ---------------------------------------------------------------------------
// Pass 1: 16-lanes-per-edge scoring. Lane l of the group reads float4 #l of
// each 256B node row -> fully coalesced. 4 shfl_xor stages reduce within the
// 16-lane group. Group leader writes ea/tt/uu and bumps den_src / cnt.
//   a = [ef,h_src,h_dst]·wg ; t = h_src·wa[0:64] ; u = ef·wa[64:96]
// ---------------------------------------------------------------------------
__global__ __launch_bounds__(256) void k_edge(
    const float* __restrict__ h, const float* __restrict__ ef,
    const int* __restrict__ src, const int* __restrict__ dst,
    const float* __restrict__ wg, const float* __restrict__ wa,
    float* __restrict__ den_src, int* __restrict__ cnt,
    float* __restrict__ ea, float* __restrict__ tt, float* __restrict__ uu)
{
    __shared__ float4 lw[40];   // wg: [0:8)=ef, [8:24)=h_src, [24:40)=h_dst
    __shared__ float4 la[24];   // wa: [0:16)=h_src, [16:24)=ef
    int tid = threadIdx.x;
    if (tid < 40)      lw[tid]      = ((const float4*)wg)[tid];
    else if (tid < 64) la[tid - 40] = ((const float4*)wa)[tid - 40];
    __syncthreads();
    int e = blockIdx.x * 16 + (tid >> 4);
    if (e >= NE) return;
    int l16 = tid & 15;
    int s = src[e], d = dst[e];
    float4 hs = ((const float4*)(h + (size_t)s * 64))[l16];
    float4 hd = ((const float4*)(h + (size_t)d * 64))[l16];
    float4 ws = lw[8 + l16], wd = lw[24 + l16], w2 = la[l16];
    float a = hs.x*ws.x + hs.y*ws.y + hs.z*ws.z + hs.w*ws.w
            + hd.x*wd.x + hd.y*wd.y + hd.z*wd.z + hd.w*wd.w;
    float t = hs.x*w2.x + hs.y*w2.y + hs.z*w2.z + hs.w*w2.w;
    float u = 0.f;
    if (l16 < 8) {
        float4 ev = ((const float4*)(ef + (size_t)e * 32))[l16];
        float4 we = lw[l16], wu = la[16 + l16];
        a += ev.x*we.x + ev.y*we.y + ev.z*we.z + ev.w*we.w;
        u  = ev.x*wu.x + ev.y*wu.y + ev.z*wu.z + ev.w*wu.w;
    }
    #pragma unroll
    for (int m = 8; m; m >>= 1) {
        a += __shfl_xor(a, m);
        t += __shfl_xor(t, m);
        u += __shfl_xor(u, m);
    }
    if (l16 == 0) {
        float evx = __expf(a);
        ea[e] = evx; tt[e] = t; uu[e] = u;
        atomicAdd(&den_src[s], evx);
        atomicAdd(&cnt[d], 1);
    }
}

// ---------------------------------------------------------------------------
// Pass 2: assign contiguous (order-arbitrary) segment bases.
// Wave-level prefix sum of cnt + one global atomic ticket per wave.
// ---------------------------------------------------------------------------
__global__ __launch_bounds__(256) void k_assign(
    const int* __restrict__ cnt, int* __restrict__ off, int* __restrict__ gtotal)
{
    int n = blockIdx.x * 256 + threadIdx.x;
    int lane = threadIdx.x & 63;
    int c = (n < NN) ? cnt[n] : 0;
    int pre = c;
    #pragma unroll
    for (int d = 1; d < 64; d <<= 1) {
        int v = __shfl_up(pre, d);
        if (lane >= d) pre += v;
    }
    int base = 0;
    if (lane == 63) base = atomicAdd(gtotal, pre);
    base = __shfl(base, 63);
    if (n < NN) off[n] = base + pre - c;
}

// ---------------------------------------------------------------------------
// Pass 3: gamma = ea/den_src[src]; s = t + gamma*u; es = exp(s);
// route 16B record {src, edge, es, gamma} into its dst segment slot.
// ---------------------------------------------------------------------------
__global__ __launch_bounds__(256) void k_route(
    const int* __restrict__ src, const int* __restrict__ dst,
    const float* __restrict__ den_src, const float* __restrict__ ea,
    const float* __restrict__ tt, const float* __restrict__ uu,
    const int* __restrict__ off, int* __restrict__ cur,
    int4* __restrict__ rec)
{
    int e = blockIdx.x * 256 + threadIdx.x;
    if (e >= NE) return;
    int s = src[e], d = dst[e];
    float g  = ea[e] / den_src[s];
    float es = __expf(tt[e] + g * uu[e]);
    int pos = off[d] + atomicAdd(&cur[d], 1);
    rec[pos] = make_int4(s, e, __float_as_int(es), __float_as_int(g));
}

// ---------------------------------------------------------------------------
// Pass 4: wave-per-node segmented reduce, 2-way unrolled for MLP.
// Lane l accumulates h-component l (64) and, for l<32, e-component l.
// Softmax denominator accumulated inline; one normalized store per node.
// ---------------------------------------------------------------------------
__global__ __launch_bounds__(256) void k_reduce(
    const float* __restrict__ h, const float* __restrict__ ef,
    const int* __restrict__ cnt, const int* __restrict__ off,
    const int4* __restrict__ rec, float* __restrict__ accum)
{
    int n = blockIdx.x * 4 + (threadIdx.x >> 6);
    if (n >= NN) return;
    int lane = threadIdx.x & 63;
    int deg = cnt[n], base = off[n];
    float acc = 0.f, acce = 0.f, den = 0.f;
    int j = 0;
    for (; j + 2 <= deg; j += 2) {
        int4 ra = rec[base + j];
        int4 rb = rec[base + j + 1];
        float esa = __int_as_float(ra.z), ga = __int_as_float(ra.w);
        float esb = __int_as_float(rb.z), gb = __int_as_float(rb.w);
        float va = h[(size_t)ra.x * 64 + lane];
        float vb = h[(size_t)rb.x * 64 + lane];
        den += esa + esb;
        acc += esa * va + esb * vb;
        if (lane < 32) {
            float ea_ = ef[(size_t)ra.y * 32 + lane];
            float eb_ = ef[(size_t)rb.y * 32 + lane];
            acce += esa * ga * ea_ + esb * gb * eb_;
        }
    }
    if (j < deg) {
        int4 r = rec[base + j];
        float es = __int_as_float(r.z), g = __int_as_float(r.w);
        den += es;
        acc += es * h[(size_t)r.x * 64 + lane];
        if (lane < 32) acce += es * g * ef[(size_t)r.y * 32 + lane];
    }
    float inv = (deg > 0) ? 1.f / den : 0.f;
    accum[(size_t)n * 96 + lane] = acc * inv;
    if (lane < 32) accum[(size_t)n * 96 + 64 + lane] = acce * inv;
}

// ---------------------------------------------------------------------------
// Pass 5: out = relu(concat([h, accum]) @ w_lin). w_lin in 40KB LDS.
// ---------------------------------------------------------------------------
__global__ __launch_bounds__(256) void k_node_update(
    const float* __restrict__ h, const float* __restrict__ accum,
    const float* __restrict__ wl_g, float* __restrict__ out)
{
    __shared__ float wl[160 * 64];
    for (int i = threadIdx.x; i < 160 * 64; i += 256) wl[i] = wl_g[i];
    __syncthreads();
    int o = threadIdx.x & 63;
    int nsub = threadIdx.x >> 6;
    for (int n = blockIdx.x * 4 + nsub; n < NN; n += gridDim.x * 4) {
        const float4* h4 = (const float4*)(h + (size_t)n * 64);
        const float4* a4 = (const float4*)(accum + (size_t)n * 96);
        float acc = 0.f;
        #pragma unroll
        for (int q = 0; q < 16; ++q) {
            float4 v = h4[q];
            int k = q * 4;
            acc += v.x * wl[(k + 0) * 64 + o] + v.y * wl[(k + 1) * 64 + o]
                 + v.z * wl[(k + 2) * 64 + o] + v.w * wl[(k + 3) * 64 + o];
        }
        #pragma unroll
        for (int q = 0; q < 24; ++q) {
            float4 v = a4[q];
            int k = 64 + q * 4;
            acc += v.x * wl[(k + 0) * 64 + o] + v.y * wl[(k + 1) * 64 + o]
                 + v.z * wl[(k + 2) * 64 + o] + v.w * wl[(k + 3) * 64 + o];
        }
        out[(size_t)n * 64 + o] = fmaxf(acc, 0.f);
    }
}

// ---------------------------------------------------------------------------
// Workspace layout (4-byte words):
//   [0, NN)                  den_src (float, zeroed)
//   [NN, 2NN)                cnt     (int,   zeroed)
//   [2NN, 3NN)               cur     (int,   zeroed)
//   [3NN, 3NN+16)            gtotal  (int,   zeroed; padded)
//   [3NN+16, 4NN+17)         off     (int)
//   [4NN+32, +4NE)           rec     (int4 x NE; 16B aligned)
//   [4NN+32+4NE, ...)        ea, tt, uu (NE each); accum (96NN) aliases ea
// total = 4NN+32 + 4NE + max(3NE, 96NN) words ≈ 32.8 MB
// ---------------------------------------------------------------------------
extern "C" void kernel_launch(void* const* d_in, const int* in_sizes, int n_in,
                              void* d_out, int out_size, void* d_ws, size_t ws_size,
                              hipStream_t stream)
{
    const float* h   = (const float*)d_in[0];
    const float* ef  = (const float*)d_in[1];
    const int*   src = (const int*)d_in[2];
    const int*   dst = (const int*)d_in[3];
    const float* wg  = (const float*)d_in[4];
    const float* wa  = (const float*)d_in[5];
    const float* wl  = (const float*)d_in[6];
    float* out = (float*)d_out;

    float* ws = (float*)d_ws;
    float* den_src = ws;
    int*   cnt = (int*)(ws + NN);
    int*   cur = (int*)(ws + 2 * NN);
    int*   gtotal = (int*)(ws + 3 * NN);
    int*   off = (int*)(ws + 3 * NN + 16);
    int4*  rec = (int4*)(ws + 4 * NN + 32);
    float* ea  = ws + 4 * NN + 32 + 4 * NE;
    float* tt  = ea + NE;
    float* uu  = tt + NE;
    float* accum = ea;   // aliases ea/tt/uu region (dead by pass 4)

    // zero den_src + cnt + cur + gtotal
    hipMemsetAsync(d_ws, 0, (size_t)(3 * NN + 16) * sizeof(float), stream);

    k_edge<<<(NE + 15) / 16, 256, 0, stream>>>(h, ef, src, dst, wg, wa,
                                               den_src, cnt, ea, tt, uu);
    k_assign<<<(NN + 255) / 256, 256, 0, stream>>>(cnt, off, gtotal);
    k_route<<<(NE + 255) / 256, 256, 0, stream>>>(src, dst, den_src, ea, tt, uu,
                                                  off, cur, rec);
    k_reduce<<<(NN + 3) / 4, 256, 0, stream>>>(h, ef, cnt, off, rec, accum);
    k_node_update<<<1024, 256, 0, stream>>>(h, accum, wl, out);
}

// Round 4
// 427.881 us; speedup vs baseline: 1.7943x; 1.1325x over previous
//
#include <hip/hip_runtime.h>

#define NN 50000
#define NE 800000
// inputs: node_features[NN*64] f32, edge_features[NE*32] f32, src[NE] i32,
//         dst[NE] i32, w_group[160] f32, w_srcattn[96] f32, w_lin[160*64] f32
// out: [NN*64] f32
//
// Algebra: a = ef·wg[0:32] + p1[src] + p2[dst]   (p1 = h·wg[32:96], p2 = h·wg[96:160])
//          t = p3[src]                           (p3 = h·wa[0:64])
//          u = ef·wa[64:96]
//          gamma = e^a / den_src[src]; s = t + gamma*u
// dst-softmax denominator = sum of e^s over a contiguous CSR segment -> no atomics.

// ---------------------------------------------------------------------------
// Pass 0: histogram of dst (for CSR offsets).
// ---------------------------------------------------------------------------
__global__ __launch_bounds__(256) void k_hist(const int* __restrict__ dst,
                                              int* __restrict__ cnt)
{
    int e = blockIdx.x * 256 + threadIdx.x;
    if (e < NE) atomicAdd(&cnt[dst[e]], 1);
}

// ---------------------------------------------------------------------------
// Pass 1: per-node projections. 16 lanes/node; lane reads one float4 of the
// 256B row, 3 dots vs LDS-staged weights, 4-stage shfl reduce.
// ps[n] = {h·wg[32:96], h·wa[0:64]} ; pd[n] = h·wg[96:160]
// ---------------------------------------------------------------------------
__global__ __launch_bounds__(256) void k_proj(
    const float* __restrict__ h, const float* __restrict__ wg,
    const float* __restrict__ wa, float2* __restrict__ ps,
    float* __restrict__ pd)
{
    __shared__ float4 ls[16], ld[16], lt[16];
    int tid = threadIdx.x;
    if (tid < 16)      ls[tid]      = ((const float4*)wg)[8 + tid];   // wg[32:96)
    else if (tid < 32) ld[tid - 16] = ((const float4*)wg)[8 + tid];   // wg[96:160)
    else if (tid < 48) lt[tid - 32] = ((const float4*)wa)[tid - 32];  // wa[0:64)
    __syncthreads();
    int n = blockIdx.x * 16 + (tid >> 4);
    if (n >= NN) return;
    int l16 = tid & 15;
    float4 v = ((const float4*)(h + (size_t)n * 64))[l16];
    float4 w1 = ls[l16], w2 = ld[l16], w3 = lt[l16];
    float s1 = v.x*w1.x + v.y*w1.y + v.z*w1.z + v.w*w1.w;
    float s2 = v.x*w2.x + v.y*w2.y + v.z*w2.z + v.w*w2.w;
    float s3 = v.x*w3.x + v.y*w3.y + v.z*w3.z + v.w*w3.w;
    #pragma unroll
    for (int m = 8; m; m >>= 1) {
        s1 += __shfl_xor(s1, m);
        s2 += __shfl_xor(s2, m);
        s3 += __shfl_xor(s3, m);
    }
    if (l16 == 0) { ps[n] = make_float2(s1, s3); pd[n] = s2; }
}

// ---------------------------------------------------------------------------
// Pass 2: contiguous (order-arbitrary) segment bases from cnt.
// ---------------------------------------------------------------------------
__global__ __launch_bounds__(256) void k_assign(
    const int* __restrict__ cnt, int* __restrict__ off, int* __restrict__ gtotal)
{
    int n = blockIdx.x * 256 + threadIdx.x;
    int lane = threadIdx.x & 63;
    int c = (n < NN) ? cnt[n] : 0;
    int pre = c;
    #pragma unroll
    for (int d = 1; d < 64; d <<= 1) {
        int v = __shfl_up(pre, d);
        if (lane >= d) pre += v;
    }
    int base = 0;
    if (lane == 63) base = atomicAdd(gtotal, pre);
    base = __shfl(base, 63);
    if (n < NN) off[n] = base + pre - c;
}

// ---------------------------------------------------------------------------
// Pass 3: thread-per-edge scoring + direct CSR routing.
// Only streams ef (own 128B row = 1 cache line) + tiny L2-resident gathers.
// recA[pos] = {src, e, e^a, u}
// ---------------------------------------------------------------------------
__global__ __launch_bounds__(256) void k_edge(
    const float* __restrict__ ef, const int* __restrict__ src,
    const int* __restrict__ dst, const float* __restrict__ wg,
    const float* __restrict__ wa, const float2* __restrict__ ps,
    const float* __restrict__ pd, float* __restrict__ den_src,
    const int* __restrict__ off, int* __restrict__ cur,
    int4* __restrict__ recA)
{
    __shared__ float4 lwe[8], lae[8];
    int tid = threadIdx.x;
    if (tid < 8)       lwe[tid]     = ((const float4*)wg)[tid];        // wg[0:32)
    else if (tid < 16) lae[tid - 8] = ((const float4*)wa)[tid - 8 + 16]; // wa[64:96)
    __syncthreads();
    int e = blockIdx.x * 256 + tid;
    if (e >= NE) return;
    int s = src[e], d = dst[e];
    const float4* e4 = (const float4*)(ef + (size_t)e * 32);
    float a = 0.f, u = 0.f;
    #pragma unroll
    for (int q = 0; q < 8; ++q) {
        float4 v = e4[q], w = lwe[q], w2 = lae[q];
        a += v.x*w.x  + v.y*w.y  + v.z*w.z  + v.w*w.w;
        u += v.x*w2.x + v.y*w2.y + v.z*w2.z + v.w*w2.w;
    }
    float2 p = ps[s];
    a += p.x + pd[d];
    float eav = __expf(a);
    atomicAdd(&den_src[s], eav);
    int pos = off[d] + atomicAdd(&cur[d], 1);
    recA[pos] = make_int4(s, e, __float_as_int(eav), __float_as_int(u));
}

// ---------------------------------------------------------------------------
// Pass 4: wave-per-node segmented softmax-reduce, 4-way unrolled.
// gamma/es computed lazily (den_src & ps are L2-resident). Lane l accumulates
// h-component l; lanes<32 accumulate e-component from random 128B ef rows.
// ---------------------------------------------------------------------------
__global__ __launch_bounds__(256) void k_reduce(
    const float* __restrict__ h, const float* __restrict__ ef,
    const int* __restrict__ cnt, const int* __restrict__ off,
    const float* __restrict__ den_src, const float2* __restrict__ ps,
    const int4* __restrict__ recA, float* __restrict__ accum)
{
    int n = blockIdx.x * 4 + (threadIdx.x >> 6);
    if (n >= NN) return;
    int lane = threadIdx.x & 63;
    int deg = cnt[n], base = off[n];
    float acch = 0.f, acce = 0.f, den = 0.f;
    int j = 0;
    for (; j + 4 <= deg; j += 4) {
        int4 r0 = recA[base+j+0], r1 = recA[base+j+1];
        int4 r2 = recA[base+j+2], r3 = recA[base+j+3];
        float d0 = den_src[r0.x], d1 = den_src[r1.x];
        float d2 = den_src[r2.x], d3 = den_src[r3.x];
        float t0 = ps[r0.x].y, t1 = ps[r1.x].y, t2 = ps[r2.x].y, t3 = ps[r3.x].y;
        float h0 = h[(size_t)r0.x*64+lane], h1 = h[(size_t)r1.x*64+lane];
        float h2 = h[(size_t)r2.x*64+lane], h3 = h[(size_t)r3.x*64+lane];
        float e0 = 0.f, e1 = 0.f, e2 = 0.f, e3 = 0.f;
        if (lane < 32) {
            e0 = ef[(size_t)r0.y*32+lane]; e1 = ef[(size_t)r1.y*32+lane];
            e2 = ef[(size_t)r2.y*32+lane]; e3 = ef[(size_t)r3.y*32+lane];
        }
        float g0 = __int_as_float(r0.z)/d0, g1 = __int_as_float(r1.z)/d1;
        float g2 = __int_as_float(r2.z)/d2, g3 = __int_as_float(r3.z)/d3;
        float s0 = __expf(t0 + g0*__int_as_float(r0.w));
        float s1 = __expf(t1 + g1*__int_as_float(r1.w));
        float s2 = __expf(t2 + g2*__int_as_float(r2.w));
        float s3 = __expf(t3 + g3*__int_as_float(r3.w));
        den  += s0 + s1 + s2 + s3;
        acch += s0*h0 + s1*h1 + s2*h2 + s3*h3;
        acce += s0*g0*e0 + s1*g1*e1 + s2*g2*e2 + s3*g3*e3;
    }
    for (; j < deg; ++j) {
        int4 r = recA[base+j];
        float dd = den_src[r.x], t = ps[r.x].y;
        float g = __int_as_float(r.z)/dd;
        float s = __expf(t + g*__int_as_float(r.w));
        den += s;
        acch += s * h[(size_t)r.x*64+lane];
        if (lane < 32) acce += s * g * ef[(size_t)r.y*32+lane];
    }
    float inv = (deg > 0) ? 1.f/den : 0.f;
    accum[(size_t)n*96 + lane] = acch * inv;
    if (lane < 32) accum[(size_t)n*96 + 64 + lane] = acce * inv;
}

// ---------------------------------------------------------------------------
// Pass 5: out = relu(concat([h, accum]) @ w_lin). w_lin in 40KB LDS.
// ---------------------------------------------------------------------------
__global__ __launch_bounds__(256) void k_node_update(
    const float* __restrict__ h, const float* __restrict__ accum,
    const float* __restrict__ wl_g, float* __restrict__ out)
{
    __shared__ float wl[160 * 64];
    for (int i = threadIdx.x; i < 160 * 64; i += 256) wl[i] = wl_g[i];
    __syncthreads();
    int o = threadIdx.x & 63;
    int nsub = threadIdx.x >> 6;
    for (int n = blockIdx.x * 4 + nsub; n < NN; n += gridDim.x * 4) {
        const float4* h4 = (const float4*)(h + (size_t)n * 64);
        const float4* a4 = (const float4*)(accum + (size_t)n * 96);
        float acc = 0.f;
        #pragma unroll
        for (int q = 0; q < 16; ++q) {
            float4 v = h4[q];
            int k = q * 4;
            acc += v.x * wl[(k + 0) * 64 + o] + v.y * wl[(k + 1) * 64 + o]
                 + v.z * wl[(k + 2) * 64 + o] + v.w * wl[(k + 3) * 64 + o];
        }
        #pragma unroll
        for (int q = 0; q < 24; ++q) {
            float4 v = a4[q];
            int k = 64 + q * 4;
            acc += v.x * wl[(k + 0) * 64 + o] + v.y * wl[(k + 1) * 64 + o]
                 + v.z * wl[(k + 2) * 64 + o] + v.w * wl[(k + 3) * 64 + o];
        }
        out[(size_t)n * 64 + o] = fmaxf(acc, 0.f);
    }
}

// ---------------------------------------------------------------------------
// Workspace layout (4-byte words):
//   [0, NN)             den_src (float, zeroed)
//   [NN, 2NN)           cnt     (int,   zeroed)
//   [2NN, 3NN)          cur     (int,   zeroed)
//   [3NN, 3NN+16)       gtotal  (int,   zeroed)
//   [3NN+16, 4NN+16)    off     (int)
//   [4NN+16, 6NN+16)    ps      (float2; byte-off 800064 %8==0)
//   [6NN+16, 7NN+16)    pd      (float)
//   [7NN+16, +4NE)      recA    (int4; byte-off 1400064 %16==0)
//   [7NN+16+4NE, +96NN) accum
// total = 103*NN + 4*NE + 16 words ≈ 33.4 MB
// ---------------------------------------------------------------------------
extern "C" void kernel_launch(void* const* d_in, const int* in_sizes, int n_in,
                              void* d_out, int out_size, void* d_ws, size_t ws_size,
                              hipStream_t stream)
{
    const float* h   = (const float*)d_in[0];
    const float* ef  = (const float*)d_in[1];
    const int*   src = (const int*)d_in[2];
    const int*   dst = (const int*)d_in[3];
    const float* wg  = (const float*)d_in[4];
    const float* wa  = (const float*)d_in[5];
    const float* wl  = (const float*)d_in[6];
    float* out = (float*)d_out;

    float* ws = (float*)d_ws;
    float*  den_src = ws;
    int*    cnt    = (int*)(ws + NN);
    int*    cur    = (int*)(ws + 2 * NN);
    int*    gtotal = (int*)(ws + 3 * NN);
    int*    off    = (int*)(ws + 3 * NN + 16);
    float2* ps     = (float2*)(ws + 4 * NN + 16);
    float*  pd     = ws + 6 * NN + 16;
    int4*   recA   = (int4*)(ws + 7 * NN + 16);
    float*  accum  = ws + 7 * NN + 16 + 4 * NE;

    hipMemsetAsync(d_ws, 0, (size_t)(3 * NN + 16) * sizeof(float), stream);

    k_hist<<<(NE + 255) / 256, 256, 0, stream>>>(dst, cnt);
    k_proj<<<(NN + 15) / 16, 256, 0, stream>>>(h, wg, wa, ps, pd);
    k_assign<<<(NN + 255) / 256, 256, 0, stream>>>(cnt, off, gtotal);
    k_edge<<<(NE + 255) / 256, 256, 0, stream>>>(ef, src, dst, wg, wa, ps, pd,
                                                 den_src, off, cur, recA);
    k_reduce<<<(NN + 3) / 4, 256, 0, stream>>>(h, ef, cnt, off, den_src, ps,
                                               recA, accum);
    k_node_update<<<1024, 256, 0, stream>>>(h, accum, wl, out);
}

// Round 5
// 403.276 us; speedup vs baseline: 1.9038x; 1.0610x over previous
//
#include <hip/hip_runtime.h>

#define NN 50000
#define NE 800000
#define NHB 3125   // NE/256 hist blocks == NN/16 proj blocks (both exact)
// inputs: node_features[NN*64] f32, edge_features[NE*32] f32, src[NE] i32,
//         dst[NE] i32, w_group[160] f32, w_srcattn[96] f32, w_lin[160*64] f32
// out: [NN*64] f32
//
// Algebra: a = ef·wg[0:32] + p1[src] + p2[dst]; t = p3[src]; u = ef·wa[64:96]
//          gamma = e^a / den_src[src]; s = t + gamma*u
// dst-CSR built via hist(rank)+assign; dst-softmax denom = inline segment sum.

// ---------------------------------------------------------------------------
// Pass 0 (fused): blocks [0,NHB): dst histogram + per-edge rank (the atomic
// return's only consumer is a coalesced 4B store -> latency trivially hidden).
// blocks [NHB,2*NHB): per-node projections (16 lanes/node, shfl reduce).
//   p1 = h·wg[32:96] ; pd = h·wg[96:160] ; dp[n].y = h·wa[0:64] (p3)
// ---------------------------------------------------------------------------
__global__ __launch_bounds__(256) void k_pre(
    const float* __restrict__ h, const int* __restrict__ dst,
    const float* __restrict__ wg, const float* __restrict__ wa,
    int* __restrict__ cnt, int* __restrict__ rank,
    float* __restrict__ p1, float* __restrict__ pd, float* __restrict__ dpf)
{
    int tid = threadIdx.x;
    if (blockIdx.x < NHB) {
        int e = blockIdx.x * 256 + tid;
        if (e < NE) rank[e] = atomicAdd(&cnt[dst[e]], 1);
        return;
    }
    __shared__ float4 ls[16], ld[16], lt[16];
    if (tid < 16)      ls[tid]      = ((const float4*)wg)[8 + tid];   // wg[32:96)
    else if (tid < 32) ld[tid - 16] = ((const float4*)wg)[8 + tid];   // wg[96:160)
    else if (tid < 48) lt[tid - 32] = ((const float4*)wa)[tid - 32];  // wa[0:64)
    __syncthreads();
    int n = (blockIdx.x - NHB) * 16 + (tid >> 4);
    if (n >= NN) return;
    int l16 = tid & 15;
    float4 v = ((const float4*)(h + (size_t)n * 64))[l16];
    float4 w1 = ls[l16], w2 = ld[l16], w3 = lt[l16];
    float s1 = v.x*w1.x + v.y*w1.y + v.z*w1.z + v.w*w1.w;
    float s2 = v.x*w2.x + v.y*w2.y + v.z*w2.z + v.w*w2.w;
    float s3 = v.x*w3.x + v.y*w3.y + v.z*w3.z + v.w*w3.w;
    #pragma unroll
    for (int m = 8; m; m >>= 1) {
        s1 += __shfl_xor(s1, m);
        s2 += __shfl_xor(s2, m);
        s3 += __shfl_xor(s3, m);
    }
    if (l16 == 0) { p1[n] = s1; pd[n] = s2; dpf[2 * n + 1] = s3; }
}

// ---------------------------------------------------------------------------
// Pass 1: contiguous (order-arbitrary) segment bases from cnt.
// ---------------------------------------------------------------------------
__global__ __launch_bounds__(256) void k_assign(
    const int* __restrict__ cnt, int* __restrict__ off, int* __restrict__ gtotal)
{
    int n = blockIdx.x * 256 + threadIdx.x;
    int lane = threadIdx.x & 63;
    int c = (n < NN) ? cnt[n] : 0;
    int pre = c;
    #pragma unroll
    for (int d = 1; d < 64; d <<= 1) {
        int v = __shfl_up(pre, d);
        if (lane >= d) pre += v;
    }
    int base = 0;
    if (lane == 63) base = atomicAdd(gtotal, pre);
    base = __shfl(base, 63);
    if (n < NN) off[n] = base + pre - c;
}

// ---------------------------------------------------------------------------
// Pass 2: thread-per-edge scoring + direct CSR routing. NO atomic-with-return:
// pos = off[dst] + rank[e]. den atomic is fire-and-forget.
// recA[pos] = {src, e, e^a, u}
// ---------------------------------------------------------------------------
__global__ __launch_bounds__(256) void k_edge(
    const float* __restrict__ ef, const int* __restrict__ src,
    const int* __restrict__ dst, const int* __restrict__ rank,
    const float* __restrict__ wg, const float* __restrict__ wa,
    const float* __restrict__ p1, const float* __restrict__ pd,
    float* __restrict__ dpf, const int* __restrict__ off,
    int4* __restrict__ recA)
{
    __shared__ float4 lwe[8], lae[8];
    int tid = threadIdx.x;
    if (tid < 8)       lwe[tid]     = ((const float4*)wg)[tid];          // wg[0:32)
    else if (tid < 16) lae[tid - 8] = ((const float4*)wa)[tid - 8 + 16]; // wa[64:96)
    __syncthreads();
    int e = blockIdx.x * 256 + tid;
    if (e >= NE) return;
    int s = src[e], d = dst[e], rk = rank[e];
    const float4* e4 = (const float4*)(ef + (size_t)e * 32);
    float a = 0.f, u = 0.f;
    #pragma unroll
    for (int q = 0; q < 8; ++q) {
        float4 v = e4[q], w = lwe[q], w2 = lae[q];
        a += v.x*w.x  + v.y*w.y  + v.z*w.z  + v.w*w.w;
        u += v.x*w2.x + v.y*w2.y + v.z*w2.z + v.w*w2.w;
    }
    a += p1[s] + pd[d];
    float eav = __expf(a);
    atomicAdd(&dpf[2 * s], eav);           // den_src; no return needed
    int pos = off[d] + rk;
    recA[pos] = make_int4(s, e, __float_as_int(eav), __float_as_int(u));
}

// ---------------------------------------------------------------------------
// Pass 3: wave-per-node segmented softmax-reduce, 4-way unrolled.
// dp[n] = {den_src, p3} -> one 8B broadcast gather per record.
// ef rows of two records per wave-wide load (lanes>=32 take the odd record);
// one shfl_xor(32) fold after the loop.
// ---------------------------------------------------------------------------
__global__ __launch_bounds__(256) void k_reduce(
    const float* __restrict__ h, const float* __restrict__ ef,
    const int* __restrict__ cnt, const int* __restrict__ off,
    const float2* __restrict__ dp, const int4* __restrict__ recA,
    float* __restrict__ accum)
{
    int n = blockIdx.x * 4 + (threadIdx.x >> 6);
    if (n >= NN) return;
    int lane = threadIdx.x & 63;
    bool up = lane >= 32;
    int l5 = lane & 31;
    int deg = cnt[n], base = off[n];
    float acch = 0.f, acce = 0.f, den = 0.f;
    int j = 0;
    for (; j + 4 <= deg; j += 4) {
        int4 r0 = recA[base+j+0], r1 = recA[base+j+1];
        int4 r2 = recA[base+j+2], r3 = recA[base+j+3];
        float2 d0 = dp[r0.x], d1 = dp[r1.x], d2 = dp[r2.x], d3 = dp[r3.x];
        float h0 = h[(size_t)r0.x*64+lane], h1 = h[(size_t)r1.x*64+lane];
        float h2 = h[(size_t)r2.x*64+lane], h3 = h[(size_t)r3.x*64+lane];
        int eA = up ? r1.y : r0.y, eB = up ? r3.y : r2.y;
        float efA = ef[(size_t)eA*32 + l5];
        float efB = ef[(size_t)eB*32 + l5];
        float g0 = __int_as_float(r0.z)/d0.x, g1 = __int_as_float(r1.z)/d1.x;
        float g2 = __int_as_float(r2.z)/d2.x, g3 = __int_as_float(r3.z)/d3.x;
        float s0 = __expf(d0.y + g0*__int_as_float(r0.w));
        float s1 = __expf(d1.y + g1*__int_as_float(r1.w));
        float s2 = __expf(d2.y + g2*__int_as_float(r2.w));
        float s3 = __expf(d3.y + g3*__int_as_float(r3.w));
        den  += s0 + s1 + s2 + s3;
        acch += s0*h0 + s1*h1 + s2*h2 + s3*h3;
        float wA = up ? s1*g1 : s0*g0;
        float wB = up ? s3*g3 : s2*g2;
        acce += wA*efA + wB*efB;
    }
    for (; j < deg; ++j) {
        int4 r = recA[base+j];
        float2 dt = dp[r.x];
        float g = __int_as_float(r.z)/dt.x;
        float s = __expf(dt.y + g*__int_as_float(r.w));
        den += s;
        acch += s * h[(size_t)r.x*64+lane];
        if (!up) acce += s * g * ef[(size_t)r.y*32 + l5];
    }
    acce += __shfl_xor(acce, 32);          // fold odd-record (upper-lane) part
    float inv = (deg > 0) ? 1.f/den : 0.f;
    accum[(size_t)n*96 + lane] = acch * inv;
    if (!up) accum[(size_t)n*96 + 64 + lane] = acce * inv;
}

// ---------------------------------------------------------------------------
// Pass 4: out = relu(concat([h, accum]) @ w_lin). w_lin in 40KB LDS.
// ---------------------------------------------------------------------------
__global__ __launch_bounds__(256) void k_node_update(
    const float* __restrict__ h, const float* __restrict__ accum,
    const float* __restrict__ wl_g, float* __restrict__ out)
{
    __shared__ float wl[160 * 64];
    for (int i = threadIdx.x; i < 160 * 64; i += 256) wl[i] = wl_g[i];
    __syncthreads();
    int o = threadIdx.x & 63;
    int nsub = threadIdx.x >> 6;
    for (int n = blockIdx.x * 4 + nsub; n < NN; n += gridDim.x * 4) {
        const float4* h4 = (const float4*)(h + (size_t)n * 64);
        const float4* a4 = (const float4*)(accum + (size_t)n * 96);
        float acc = 0.f;
        #pragma unroll
        for (int q = 0; q < 16; ++q) {
            float4 v = h4[q];
            int k = q * 4;
            acc += v.x * wl[(k + 0) * 64 + o] + v.y * wl[(k + 1) * 64 + o]
                 + v.z * wl[(k + 2) * 64 + o] + v.w * wl[(k + 3) * 64 + o];
        }
        #pragma unroll
        for (int q = 0; q < 24; ++q) {
            float4 v = a4[q];
            int k = 64 + q * 4;
            acc += v.x * wl[(k + 0) * 64 + o] + v.y * wl[(k + 1) * 64 + o]
                 + v.z * wl[(k + 2) * 64 + o] + v.w * wl[(k + 3) * 64 + o];
        }
        out[(size_t)n * 64 + o] = fmaxf(acc, 0.f);
    }
}

// ---------------------------------------------------------------------------
// Workspace layout (4-byte words):
//   [0, 2NN)            dp      (float2 {den_src, p3}; zeroed)
//   [2NN, 3NN)          cnt     (int, zeroed)
//   [3NN, 3NN+16)       gtotal  (int, zeroed)
//   [3NN+16, 4NN+16)    off     (int)
//   [4NN+16, 5NN+16)    p1      (float)
//   [5NN+16, 6NN+16)    pd      (float)
//   [6NN+16, +4NE)      recA    (int4; byte off 1200064 %16==0)
//   [6NN+16+4NE, ...)   Z: rank (int, NE; dead after k_edge)
//                          accum (float, 96NN; written in k_reduce) -- aliased
// total = 6NN+16 + 4NE + 96NN words ≈ 33.2 MB
// ---------------------------------------------------------------------------
extern "C" void kernel_launch(void* const* d_in, const int* in_sizes, int n_in,
                              void* d_out, int out_size, void* d_ws, size_t ws_size,
                              hipStream_t stream)
{
    const float* h   = (const float*)d_in[0];
    const float* ef  = (const float*)d_in[1];
    const int*   src = (const int*)d_in[2];
    const int*   dst = (const int*)d_in[3];
    const float* wg  = (const float*)d_in[4];
    const float* wa  = (const float*)d_in[5];
    const float* wl  = (const float*)d_in[6];
    float* out = (float*)d_out;

    float* ws = (float*)d_ws;
    float*  dpf    = ws;                       // float2 view at same addr
    int*    cnt    = (int*)(ws + 2 * NN);
    int*    gtotal = (int*)(ws + 3 * NN);
    int*    off    = (int*)(ws + 3 * NN + 16);
    float*  p1     = ws + 4 * NN + 16;
    float*  pd     = ws + 5 * NN + 16;
    int4*   recA   = (int4*)(ws + 6 * NN + 16);
    int*    rank   = (int*)(ws + 6 * NN + 16 + 4 * NE);
    float*  accum  = ws + 6 * NN + 16 + 4 * NE;   // aliases rank (dead by then)

    hipMemsetAsync(d_ws, 0, (size_t)(3 * NN + 16) * sizeof(float), stream);

    k_pre<<<2 * NHB, 256, 0, stream>>>(h, dst, wg, wa, cnt, rank, p1, pd, dpf);
    k_assign<<<(NN + 255) / 256, 256, 0, stream>>>(cnt, off, gtotal);
    k_edge<<<NHB, 256, 0, stream>>>(ef, src, dst, rank, wg, wa, p1, pd, dpf,
                                    off, recA);
    k_reduce<<<(NN + 3) / 4, 256, 0, stream>>>(h, ef, cnt, off, (const float2*)dpf,
                                               recA, accum);
    k_node_update<<<1024, 256, 0, stream>>>(h, accum, wl, out);
}

// Round 6
// 336.586 us; speedup vs baseline: 2.2810x; 1.1981x over previous
//
#include <hip/hip_runtime.h>

#define NN 50000
#define NE 800000
#define NHB 3125   // NE/256 hist blocks == NN/16 proj blocks (both exact)
#define NTILES 3125  // NN/16 node tiles for the MFMA output GEMM
// inputs: node_features[NN*64] f32, edge_features[NE*32] f32, src[NE] i32,
//         dst[NE] i32, w_group[160] f32, w_srcattn[96] f32, w_lin[160*64] f32
// out: [NN*64] f32
//
// Algebra: a = ef·wg[0:32] + p1[src] + p2[dst]; t = p3[src]; u = ef·wa[64:96]
//          gamma = e^a / den_src[src]; s = t + gamma*u
// dst-CSR built via hist(rank)+assign; dst-softmax denom = inline segment sum.

typedef __attribute__((ext_vector_type(8))) short bf16x8;  // 8 bf16 (4 VGPRs)
typedef __attribute__((ext_vector_type(4))) float f32x4;

static __device__ __forceinline__ short f2bf(float f) {
    unsigned int u = __float_as_uint(f);
    u += 0x7FFFu + ((u >> 16) & 1u);       // round-to-nearest-even
    return (short)(u >> 16);
}

// ---------------------------------------------------------------------------
// Pass 0 (fused): blocks [0,NHB): dst histogram + per-edge rank (the atomic
// return's only consumer is a coalesced 4B store -> latency trivially hidden).
// blocks [NHB,2*NHB): per-node projections (16 lanes/node, shfl reduce).
//   p1 = h·wg[32:96] ; pd = h·wg[96:160] ; dp[n].y = h·wa[0:64] (p3)
// ---------------------------------------------------------------------------
__global__ __launch_bounds__(256) void k_pre(
    const float* __restrict__ h, const int* __restrict__ dst,
    const float* __restrict__ wg, const float* __restrict__ wa,
    int* __restrict__ cnt, int* __restrict__ rank,
    float* __restrict__ p1, float* __restrict__ pd, float* __restrict__ dpf)
{
    int tid = threadIdx.x;
    if (blockIdx.x < NHB) {
        int e = blockIdx.x * 256 + tid;
        if (e < NE) rank[e] = atomicAdd(&cnt[dst[e]], 1);
        return;
    }
    __shared__ float4 ls[16], ld[16], lt[16];
    if (tid < 16)      ls[tid]      = ((const float4*)wg)[8 + tid];   // wg[32:96)
    else if (tid < 32) ld[tid - 16] = ((const float4*)wg)[8 + tid];   // wg[96:160)
    else if (tid < 48) lt[tid - 32] = ((const float4*)wa)[tid - 32];  // wa[0:64)
    __syncthreads();
    int n = (blockIdx.x - NHB) * 16 + (tid >> 4);
    if (n >= NN) return;
    int l16 = tid & 15;
    float4 v = ((const float4*)(h + (size_t)n * 64))[l16];
    float4 w1 = ls[l16], w2 = ld[l16], w3 = lt[l16];
    float s1 = v.x*w1.x + v.y*w1.y + v.z*w1.z + v.w*w1.w;
    float s2 = v.x*w2.x + v.y*w2.y + v.z*w2.z + v.w*w2.w;
    float s3 = v.x*w3.x + v.y*w3.y + v.z*w3.z + v.w*w3.w;
    #pragma unroll
    for (int m = 8; m; m >>= 1) {
        s1 += __shfl_xor(s1, m);
        s2 += __shfl_xor(s2, m);
        s3 += __shfl_xor(s3, m);
    }
    if (l16 == 0) { p1[n] = s1; pd[n] = s2; dpf[2 * n + 1] = s3; }
}

// ---------------------------------------------------------------------------
// Pass 1: contiguous (order-arbitrary) segment bases from cnt.
// ---------------------------------------------------------------------------
__global__ __launch_bounds__(256) void k_assign(
    const int* __restrict__ cnt, int* __restrict__ off, int* __restrict__ gtotal)
{
    int n = blockIdx.x * 256 + threadIdx.x;
    int lane = threadIdx.x & 63;
    int c = (n < NN) ? cnt[n] : 0;
    int pre = c;
    #pragma unroll
    for (int d = 1; d < 64; d <<= 1) {
        int v = __shfl_up(pre, d);
        if (lane >= d) pre += v;
    }
    int base = 0;
    if (lane == 63) base = atomicAdd(gtotal, pre);
    base = __shfl(base, 63);
    if (n < NN) off[n] = base + pre - c;
}

// ---------------------------------------------------------------------------
// Pass 2: thread-per-edge scoring + direct CSR routing. NO atomic-with-return:
// pos = off[dst] + rank[e]. den atomic is fire-and-forget.
// recA[pos] = {src, e, e^a, u}
// ---------------------------------------------------------------------------
__global__ __launch_bounds__(256) void k_edge(
    const float* __restrict__ ef, const int* __restrict__ src,
    const int* __restrict__ dst, const int* __restrict__ rank,
    const float* __restrict__ wg, const float* __restrict__ wa,
    const float* __restrict__ p1, const float* __restrict__ pd,
    float* __restrict__ dpf, const int* __restrict__ off,
    int4* __restrict__ recA)
{
    __shared__ float4 lwe[8], lae[8];
    int tid = threadIdx.x;
    if (tid < 8)       lwe[tid]     = ((const float4*)wg)[tid];          // wg[0:32)
    else if (tid < 16) lae[tid - 8] = ((const float4*)wa)[tid - 8 + 16]; // wa[64:96)
    __syncthreads();
    int e = blockIdx.x * 256 + tid;
    if (e >= NE) return;
    int s = src[e], d = dst[e], rk = rank[e];
    const float4* e4 = (const float4*)(ef + (size_t)e * 32);
    float a = 0.f, u = 0.f;
    #pragma unroll
    for (int q = 0; q < 8; ++q) {
        float4 v = e4[q], w = lwe[q], w2 = lae[q];
        a += v.x*w.x  + v.y*w.y  + v.z*w.z  + v.w*w.w;
        u += v.x*w2.x + v.y*w2.y + v.z*w2.z + v.w*w2.w;
    }
    a += p1[s] + pd[d];
    float eav = __expf(a);
    atomicAdd(&dpf[2 * s], eav);           // den_src; no return needed
    int pos = off[d] + rk;
    recA[pos] = make_int4(s, e, __float_as_int(eav), __float_as_int(u));
}

// ---------------------------------------------------------------------------
// Pass 3: wave-per-node segmented softmax-reduce, 4-way unrolled.
// dp[n] = {den_src, p3} -> one 8B broadcast gather per record.
// ef rows of two records per wave-wide load (lanes>=32 take the odd record);
// one shfl_xor(32) fold after the loop.
// ---------------------------------------------------------------------------
__global__ __launch_bounds__(256) void k_reduce(
    const float* __restrict__ h, const float* __restrict__ ef,
    const int* __restrict__ cnt, const int* __restrict__ off,
    const float2* __restrict__ dp, const int4* __restrict__ recA,
    float* __restrict__ accum)
{
    int n = blockIdx.x * 4 + (threadIdx.x >> 6);
    if (n >= NN) return;
    int lane = threadIdx.x & 63;
    bool up = lane >= 32;
    int l5 = lane & 31;
    int deg = cnt[n], base = off[n];
    float acch = 0.f, acce = 0.f, den = 0.f;
    int j = 0;
    for (; j + 4 <= deg; j += 4) {
        int4 r0 = recA[base+j+0], r1 = recA[base+j+1];
        int4 r2 = recA[base+j+2], r3 = recA[base+j+3];
        float2 d0 = dp[r0.x], d1 = dp[r1.x], d2 = dp[r2.x], d3 = dp[r3.x];
        float h0 = h[(size_t)r0.x*64+lane], h1 = h[(size_t)r1.x*64+lane];
        float h2 = h[(size_t)r2.x*64+lane], h3 = h[(size_t)r3.x*64+lane];
        int eA = up ? r1.y : r0.y, eB = up ? r3.y : r2.y;
        float efA = ef[(size_t)eA*32 + l5];
        float efB = ef[(size_t)eB*32 + l5];
        float g0 = __int_as_float(r0.z)/d0.x, g1 = __int_as_float(r1.z)/d1.x;
        float g2 = __int_as_float(r2.z)/d2.x, g3 = __int_as_float(r3.z)/d3.x;
        float s0 = __expf(d0.y + g0*__int_as_float(r0.w));
        float s1 = __expf(d1.y + g1*__int_as_float(r1.w));
        float s2 = __expf(d2.y + g2*__int_as_float(r2.w));
        float s3 = __expf(d3.y + g3*__int_as_float(r3.w));
        den  += s0 + s1 + s2 + s3;
        acch += s0*h0 + s1*h1 + s2*h2 + s3*h3;
        float wA = up ? s1*g1 : s0*g0;
        float wB = up ? s3*g3 : s2*g2;
        acce += wA*efA + wB*efB;
    }
    for (; j < deg; ++j) {
        int4 r = recA[base+j];
        float2 dt = dp[r.x];
        float g = __int_as_float(r.z)/dt.x;
        float s = __expf(dt.y + g*__int_as_float(r.w));
        den += s;
        acch += s * h[(size_t)r.x*64+lane];
        if (!up) acce += s * g * ef[(size_t)r.y*32 + l5];
    }
    acce += __shfl_xor(acce, 32);          // fold odd-record (upper-lane) part
    float inv = (deg > 0) ? 1.f/den : 0.f;
    accum[(size_t)n*96 + lane] = acch * inv;
    if (!up) accum[(size_t)n*96 + 64 + lane] = acce * inv;
}

// ---------------------------------------------------------------------------
// Pass 4: out = relu(concat([h, accum]) @ w_lin) as an MFMA bf16 GEMM.
// [NN x 160] · [160 x 64]; M-tile = 16 nodes per wave, K = 5 chunks of 32,
// N = 4 tiles of 16. w_lin held as 20 B-fragments in registers per wave
// (loaded once, reused over ~3 node tiles). No LDS.
// Layouts (m89/m120-verified): A[m=lane&15][k=quad*8+j],
// B[k=quad*8+j][n=lane&15], D[row=quad*4+reg][col=lane&15].
// ---------------------------------------------------------------------------
__global__ __launch_bounds__(256) void k_node_update(
    const float* __restrict__ h, const float* __restrict__ accum,
    const float* __restrict__ wl_g, float* __restrict__ out)
{
    int lane = threadIdx.x & 63;
    int col  = lane & 15;
    int quad = lane >> 4;
    int wid  = blockIdx.x * 4 + (threadIdx.x >> 6);
    int nwaves = gridDim.x * 4;

    // --- load B fragments (w_lin -> bf16), once per wave ---
    bf16x8 bfr[5][4];
    #pragma unroll
    for (int kc = 0; kc < 5; ++kc)
        #pragma unroll
        for (int nt = 0; nt < 4; ++nt) {
            #pragma unroll
            for (int j = 0; j < 8; ++j) {
                int k = kc * 32 + quad * 8 + j;
                bfr[kc][nt][j] = f2bf(wl_g[k * 64 + nt * 16 + col]);
            }
        }

    for (int tile = wid; tile < NTILES; tile += nwaves) {
        int n = tile * 16 + col;             // A-operand node (m = lane&15)
        f32x4 acc[4];
        #pragma unroll
        for (int nt = 0; nt < 4; ++nt) acc[nt] = (f32x4){0.f, 0.f, 0.f, 0.f};

        #pragma unroll
        for (int kc = 0; kc < 5; ++kc) {
            int kbase = kc * 32 + quad * 8;  // multiples of 8; 64-boundary safe
            const float* p = (kbase < 64)
                ? (h     + (size_t)n * 64 + kbase)
                : (accum + (size_t)n * 96 + (kbase - 64));
            float4 va = *(const float4*)p;
            float4 vb = *(const float4*)(p + 4);
            bf16x8 af;
            af[0] = f2bf(va.x); af[1] = f2bf(va.y);
            af[2] = f2bf(va.z); af[3] = f2bf(va.w);
            af[4] = f2bf(vb.x); af[5] = f2bf(vb.y);
            af[6] = f2bf(vb.z); af[7] = f2bf(vb.w);
            #pragma unroll
            for (int nt = 0; nt < 4; ++nt)
                acc[nt] = __builtin_amdgcn_mfma_f32_16x16x32_bf16(
                    af, bfr[kc][nt], acc[nt], 0, 0, 0);
        }

        // D: row = quad*4 + r (node within tile), col = nt*16 + (lane&15)
        #pragma unroll
        for (int nt = 0; nt < 4; ++nt) {
            #pragma unroll
            for (int r = 0; r < 4; ++r) {
                int node = tile * 16 + quad * 4 + r;
                out[(size_t)node * 64 + nt * 16 + col] = fmaxf(acc[nt][r], 0.f);
            }
        }
    }
}

// ---------------------------------------------------------------------------
// Workspace layout (4-byte words):
//   [0, 2NN)            dp      (float2 {den_src, p3}; zeroed)
//   [2NN, 3NN)          cnt     (int, zeroed)
//   [3NN, 3NN+16)       gtotal  (int, zeroed)
//   [3NN+16, 4NN+16)    off     (int)
//   [4NN+16, 5NN+16)    p1      (float)
//   [5NN+16, 6NN+16)    pd      (float)
//   [6NN+16, +4NE)      recA    (int4; byte off 1200064 %16==0)
//   [6NN+16+4NE, ...)   Z: rank (int, NE; dead after k_edge)
//                          accum (float, 96NN; 16B-aligned) -- aliased
// total = 6NN+16 + 4NE + 96NN words ≈ 33.2 MB
// ---------------------------------------------------------------------------
extern "C" void kernel_launch(void* const* d_in, const int* in_sizes, int n_in,
                              void* d_out, int out_size, void* d_ws, size_t ws_size,
                              hipStream_t stream)
{
    const float* h   = (const float*)d_in[0];
    const float* ef  = (const float*)d_in[1];
    const int*   src = (const int*)d_in[2];
    const int*   dst = (const int*)d_in[3];
    const float* wg  = (const float*)d_in[4];
    const float* wa  = (const float*)d_in[5];
    const float* wl  = (const float*)d_in[6];
    float* out = (float*)d_out;

    float* ws = (float*)d_ws;
    float*  dpf    = ws;                       // float2 view at same addr
    int*    cnt    = (int*)(ws + 2 * NN);
    int*    gtotal = (int*)(ws + 3 * NN);
    int*    off    = (int*)(ws + 3 * NN + 16);
    float*  p1     = ws + 4 * NN + 16;
    float*  pd     = ws + 5 * NN + 16;
    int4*   recA   = (int4*)(ws + 6 * NN + 16);
    int*    rank   = (int*)(ws + 6 * NN + 16 + 4 * NE);
    float*  accum  = ws + 6 * NN + 16 + 4 * NE;   // aliases rank (dead by then)

    hipMemsetAsync(d_ws, 0, (size_t)(3 * NN + 16) * sizeof(float), stream);

    k_pre<<<2 * NHB, 256, 0, stream>>>(h, dst, wg, wa, cnt, rank, p1, pd, dpf);
    k_assign<<<(NN + 255) / 256, 256, 0, stream>>>(cnt, off, gtotal);
    k_edge<<<NHB, 256, 0, stream>>>(ef, src, dst, rank, wg, wa, p1, pd, dpf,
                                    off, recA);
    k_reduce<<<(NN + 3) / 4, 256, 0, stream>>>(h, ef, cnt, off, (const float2*)dpf,
                                               recA, accum);
    k_node_update<<<256, 256, 0, stream>>>(h, accum, wl, out);
}